// Round 3
// baseline (567.788 us; speedup 1.0000x reference)
//
#include <hip/hip_runtime.h>
#include <hip/hip_fp16.h>

// Problem constants (fixed by reference)
#define N_PTS 1048576
#define BSEG  2048
#define XSTR  72    // xfeat f16 row stride: 64 features + 8 pad (144 B, bank-spread)

typedef _Float16 half8  __attribute__((ext_vector_type(8)));
typedef _Float16 half4  __attribute__((ext_vector_type(4)));
typedef float    floatx4 __attribute__((ext_vector_type(4)));

// ---------------------------------------------------------------------------
// Kernel W: transpose + f16-convert heavy-layer weights.
// Concat order is [enc(32) | feat(64)]: w1 rows 32..95 -> w1T [128 j][64 k];
// rows 0..31 folded into per-segment bias by enc_pool. w2/w3 -> [128 j][128 k].
// ---------------------------------------------------------------------------
__global__ __launch_bounds__(256) void wconv(const float* __restrict__ w1,
                                             const float* __restrict__ w2,
                                             const float* __restrict__ w3,
                                             _Float16* __restrict__ w1T,
                                             _Float16* __restrict__ w2T,
                                             _Float16* __restrict__ w3T) {
    int idx = blockIdx.x * 256 + threadIdx.x;
    if (idx < 8192) {                         // 128*64
        int j = idx >> 6, k = idx & 63;
        w1T[idx] = (_Float16)w1[(32 + k) * 128 + j];
    } else if (idx < 8192 + 16384) {
        int i = idx - 8192; int j = i >> 7, k = i & 127;
        w2T[i] = (_Float16)w2[k * 128 + j];
    } else if (idx < 8192 + 32768) {
        int i = idx - 8192 - 16384; int j = i >> 7, k = i & 127;
        w3T[i] = (_Float16)w3[k * 128 + j];
    }
}

// ---------------------------------------------------------------------------
// Kernel A: per-segment encoder + segment-max + fold enc through W1's enc rows
// into a per-segment bias b1p[b][128] = b1 + enc . W1[0:32,:]  (fp32 exact).
// relu>=0 so init-0 max == reference's neginf->0 guard (incl. empty segments).
// ---------------------------------------------------------------------------
__global__ __launch_bounds__(256) void enc_pool(const float* __restrict__ pts,
                                                const int* __restrict__ batch,
                                                const float* __restrict__ wne,
                                                const float* __restrict__ bne,
                                                const float* __restrict__ w1,
                                                const float* __restrict__ b1,
                                                float* __restrict__ b1p) {
    const int b = blockIdx.x, tid = threadIdx.x;
    __shared__ float swne[96];
    __shared__ float sbne[32];
    __shared__ float red[4][32];
    __shared__ float sEnc[32];
    if (tid < 96) swne[tid] = wne[tid];
    if (tid < 32) sbne[tid] = bne[tid];

    int lo = 0, hi = N_PTS;
    while (lo < hi) { int mid = (lo + hi) >> 1; if (batch[mid] < b) lo = mid + 1; else hi = mid; }
    const int start = lo;
    hi = N_PTS;
    while (lo < hi) { int mid = (lo + hi) >> 1; if (batch[mid] < b + 1) lo = mid + 1; else hi = mid; }
    const int end = lo;
    __syncthreads();

    float mx[32];
#pragma unroll
    for (int j = 0; j < 32; j++) mx[j] = 0.f;
    for (int p = start + tid; p < end; p += 256) {
        float x0 = pts[3 * p], x1 = pts[3 * p + 1], x2 = pts[3 * p + 2];
#pragma unroll
        for (int j = 0; j < 32; j++) {
            float e = fmaf(x0, swne[j], fmaf(x1, swne[32 + j], fmaf(x2, swne[64 + j], sbne[j])));
            mx[j] = fmaxf(mx[j], e);
        }
    }
#pragma unroll
    for (int j = 0; j < 32; j++) {
#pragma unroll
        for (int off = 1; off < 64; off <<= 1)
            mx[j] = fmaxf(mx[j], __shfl_xor(mx[j], off, 64));
    }
    const int wv = tid >> 6;
    if ((tid & 63) == 0) {
#pragma unroll
        for (int j = 0; j < 32; j++) red[wv][j] = mx[j];
    }
    __syncthreads();
    if (tid < 32)
        sEnc[tid] = fmaxf(fmaxf(red[0][tid], red[1][tid]), fmaxf(red[2][tid], red[3][tid]));
    __syncthreads();
    if (tid < 128) {
        float acc = b1[tid];
#pragma unroll 8
        for (int k = 0; k < 32; k++) acc = fmaf(sEnc[k], w1[k * 128 + tid], acc);
        b1p[b * 128 + tid] = acc;
    }
}

// ---------------------------------------------------------------------------
// Kernel B: per-segment fused 3-layer MLP (f16 MFMA) + segment max + fp32 head.
// 256 threads = 4 waves, jsplit=4 (wave owns 32 output cols, B-frags in regs).
// SOFTWARE-PIPELINED across layers: at phase it, compute L1(it), L2(it-1),
// L3(it-2) with h1/h2 double-buffered and xf triple-buffered -> ONE barrier
// per phase, all A-frag ds_reads issued at phase start (latency overlapped).
// h layout XOR-chunk-swizzled; plain b16 stores (~2-way conflicts = free).
// ---------------------------------------------------------------------------
__global__ __launch_bounds__(256, 3) void fused_mlp(
    const float* __restrict__ feat, const int* __restrict__ batch,
    const float* __restrict__ b1p_g,
    const _Float16* __restrict__ w1T, const _Float16* __restrict__ w2T,
    const _Float16* __restrict__ w3T,
    const float* __restrict__ b2, const float* __restrict__ b3,
    const float* __restrict__ wg1, const float* __restrict__ bg1,
    const float* __restrict__ wg2, const float* __restrict__ bg2,
    const float* __restrict__ wg3, const float* __restrict__ bg3,
    float* __restrict__ out) {
    __shared__ __attribute__((aligned(16))) _Float16 xf[3][16 * XSTR];  // 6.9 KB
    __shared__ __attribute__((aligned(16))) _Float16 h1s[2][16 * 128];  // 8 KB
    __shared__ __attribute__((aligned(16))) _Float16 h2s[2][16 * 128];  // 8 KB
    __shared__ float pooled[128];
    __shared__ float g1s[128];
    __shared__ float g2s[64];

    const int b = blockIdx.x, tid = threadIdx.x;
    const int lane = tid & 63, jq = tid >> 6;
    const int l15 = lane & 15, quad = lane >> 4;

    // segment range (batch sorted)
    int lo = 0, hi = N_PTS;
    while (lo < hi) { int mid = (lo + hi) >> 1; if (batch[mid] < b) lo = mid + 1; else hi = mid; }
    const int start = lo;
    hi = N_PTS;
    while (lo < hi) { int mid = (lo + hi) >> 1; if (batch[mid] < b + 1) lo = mid + 1; else hi = mid; }
    const int end = lo;
    const int n = end - start;
    const int niter = (n + 15) >> 4;

    // B-fragments (weights), VGPR-resident: 20 half8 = 80 regs.
    // frag layout: elem t of lane = W[n = jcol][k = ks*32 + quad*8 + t]
    const int jc0 = jq * 32 + l15, jc1 = jc0 + 16;
    half8 w1f[2][2], w2f[2][4], w3f[2][4];
#pragma unroll
    for (int ks = 0; ks < 2; ks++) {
        w1f[0][ks] = *(const half8*)(w1T + jc0 * 64 + ks * 32 + quad * 8);
        w1f[1][ks] = *(const half8*)(w1T + jc1 * 64 + ks * 32 + quad * 8);
    }
#pragma unroll
    for (int ks = 0; ks < 4; ks++) {
        w2f[0][ks] = *(const half8*)(w2T + jc0 * 128 + ks * 32 + quad * 8);
        w2f[1][ks] = *(const half8*)(w2T + jc1 * 128 + ks * 32 + quad * 8);
        w3f[0][ks] = *(const half8*)(w3T + jc0 * 128 + ks * 32 + quad * 8);
        w3f[1][ks] = *(const half8*)(w3T + jc1 * 128 + ks * 32 + quad * 8);
    }
    float bb1[2], bb2[2], bb3[2];
    bb1[0] = b1p_g[b * 128 + jc0]; bb1[1] = b1p_g[b * 128 + jc1];
    bb2[0] = b2[jc0]; bb2[1] = b2[jc1];
    bb3[0] = b3[jc0]; bb3[1] = b3[jc1];

    // staging: 1 float4/thread/iter (16 rows x 64 f32)
    const int srow = tid >> 4, scol = tid & 15;
    floatx4 pf;
    auto issue = [&](int it) {
        int p = start + it * 16 + srow;
        if (p < end) pf = *(const floatx4*)(feat + (size_t)p * 64 + scol * 4);
        else         pf = (floatx4){0.f, 0.f, 0.f, 0.f};
    };
    auto commitSlot = [&](int slot) {
        half4 hv = {(_Float16)pf.x, (_Float16)pf.y, (_Float16)pf.z, (_Float16)pf.w};
        *(half4*)(&xf[slot][srow * XSTR + scol * 4]) = hv;
    };
    // swizzled h store: elem (row rr, col c) at rr*128 + (((c>>3)^rr)&15)*8 + (c&7)
    auto storeH = [&](_Float16* hbuf, floatx4* acc, float* bb) {
#pragma unroll
        for (int jt = 0; jt < 2; jt++) {
            int c = jq * 32 + jt * 16 + l15;
#pragma unroll
            for (int r = 0; r < 4; r++) {
                int rr = quad * 4 + r;
                float v = fmaxf(acc[jt][r] + bb[jt], 0.f);
                hbuf[rr * 128 + ((((c >> 3) ^ rr) & 15) << 3) + (c & 7)] = (_Float16)v;
            }
        }
    };

    // prologue: fill xf slot 0 (iter 0), preload iter 1 into pf
    if (niter > 0) { issue(0); commitSlot(0); if (niter > 1) issue(1); }
    __syncthreads();

    float vmax[2] = {0.f, 0.f};

    for (int it = 0; it < niter + 2; ++it) {
        const bool doL1 = (it < niter);
        const bool doL2 = (it >= 1) && (it <= niter);
        const bool doL3 = (it >= 2);

        // --- issue all A-frag LDS reads up front (latency overlap) ---
        half8 a3[4], a2[4], a1[2];
        if (doL3) {
            const _Float16* src = h2s[(it - 2) & 1];
#pragma unroll
            for (int ks = 0; ks < 4; ks++)
                a3[ks] = *(const half8*)(&src[(l15 << 7) + ((((ks * 4 + quad) ^ l15) & 15) << 3)]);
        }
        if (doL2) {
            const _Float16* src = h1s[(it - 1) & 1];
#pragma unroll
            for (int ks = 0; ks < 4; ks++)
                a2[ks] = *(const half8*)(&src[(l15 << 7) + ((((ks * 4 + quad) ^ l15) & 15) << 3)]);
        }
        if (doL1) {
            const _Float16* src = xf[it % 3];
#pragma unroll
            for (int ks = 0; ks < 2; ks++)
                a1[ks] = *(const half8*)(&src[l15 * XSTR + ks * 32 + quad * 8]);
        }
        // --- stage next x tiles (independent of this phase's compute) ---
        if (it + 1 < niter) commitSlot((it + 1) % 3);
        if (it + 2 < niter) issue(it + 2);

        // --- L3(it-2): h2 -> vmax ---
        if (doL3) {
            floatx4 acc[2];
            acc[0] = (floatx4){0.f, 0.f, 0.f, 0.f};
            acc[1] = (floatx4){0.f, 0.f, 0.f, 0.f};
#pragma unroll
            for (int ks = 0; ks < 4; ks++) {
                acc[0] = __builtin_amdgcn_mfma_f32_16x16x32_f16(a3[ks], w3f[0][ks], acc[0], 0, 0, 0);
                acc[1] = __builtin_amdgcn_mfma_f32_16x16x32_f16(a3[ks], w3f[1][ks], acc[1], 0, 0, 0);
            }
            const int rowbase = (it - 2) * 16 + quad * 4;
#pragma unroll
            for (int jt = 0; jt < 2; jt++) {
#pragma unroll
                for (int r = 0; r < 4; r++) {
                    float v = ((rowbase + r) < n) ? fmaxf(acc[jt][r] + bb3[jt], 0.f) : 0.f;
                    vmax[jt] = fmaxf(vmax[jt], v);
                }
            }
        }
        // --- L2(it-1): h1 -> h2 ---
        if (doL2) {
            floatx4 acc[2];
            acc[0] = (floatx4){0.f, 0.f, 0.f, 0.f};
            acc[1] = (floatx4){0.f, 0.f, 0.f, 0.f};
#pragma unroll
            for (int ks = 0; ks < 4; ks++) {
                acc[0] = __builtin_amdgcn_mfma_f32_16x16x32_f16(a2[ks], w2f[0][ks], acc[0], 0, 0, 0);
                acc[1] = __builtin_amdgcn_mfma_f32_16x16x32_f16(a2[ks], w2f[1][ks], acc[1], 0, 0, 0);
            }
            storeH(h2s[(it - 1) & 1], acc, bb2);
        }
        // --- L1(it): xf -> h1 ---
        if (doL1) {
            floatx4 acc[2];
            acc[0] = (floatx4){0.f, 0.f, 0.f, 0.f};
            acc[1] = (floatx4){0.f, 0.f, 0.f, 0.f};
#pragma unroll
            for (int ks = 0; ks < 2; ks++) {
                acc[0] = __builtin_amdgcn_mfma_f32_16x16x32_f16(a1[ks], w1f[0][ks], acc[0], 0, 0, 0);
                acc[1] = __builtin_amdgcn_mfma_f32_16x16x32_f16(a1[ks], w1f[1][ks], acc[1], 0, 0, 0);
            }
            storeH(h1s[it & 1], acc, bb1);
        }
        __syncthreads();
    }

    // cross-quad row reduction; each col owned by exactly one wave -> plain store
#pragma unroll
    for (int jt = 0; jt < 2; jt++) {
        float m = vmax[jt];
        m = fmaxf(m, __shfl_xor(m, 16, 64));
        m = fmaxf(m, __shfl_xor(m, 32, 64));
        if (quad == 0) pooled[jq * 32 + jt * 16 + l15] = m;
    }
    __syncthreads();

    // ---- fp32 head MLP (tiny, exact) ----
    if (tid < 128) {
        float acc = bg1[tid];
#pragma unroll 8
        for (int k = 0; k < 128; k++) acc = fmaf(pooled[k], wg1[k * 128 + tid], acc);
        g1s[tid] = fmaxf(acc, 0.f);
    }
    __syncthreads();
    if (tid < 64) {
        float acc = bg2[tid];
#pragma unroll 8
        for (int k = 0; k < 128; k++) acc = fmaf(g1s[k], wg2[k * 64 + tid], acc);
        g2s[tid] = fmaxf(acc, 0.f);
    }
    __syncthreads();
    if (tid < 32) {
        float acc = bg3[tid];
#pragma unroll 8
        for (int k = 0; k < 64; k++) acc = fmaf(g2s[k], wg3[k * 32 + tid], acc);
        out[b * 32 + tid] = fmaxf(acc, 0.f);
    }
}

// ---------------------------------------------------------------------------
extern "C" void kernel_launch(void* const* d_in, const int* in_sizes, int n_in,
                              void* d_out, int out_size, void* d_ws, size_t ws_size,
                              hipStream_t stream) {
    const float* points = (const float*)d_in[0];
    const float* feat   = (const float*)d_in[1];
    const int*   batch  = (const int*)d_in[2];
    const float* w_ne   = (const float*)d_in[3];
    const float* b_ne   = (const float*)d_in[4];
    const float* w1  = (const float*)d_in[5];
    const float* b1  = (const float*)d_in[6];
    const float* w2  = (const float*)d_in[7];
    const float* b2  = (const float*)d_in[8];
    const float* w3  = (const float*)d_in[9];
    const float* b3  = (const float*)d_in[10];
    const float* wg1 = (const float*)d_in[11];
    const float* bg1 = (const float*)d_in[12];
    const float* wg2 = (const float*)d_in[13];
    const float* bg2 = (const float*)d_in[14];
    const float* wg3 = (const float*)d_in[15];
    const float* bg3 = (const float*)d_in[16];
    float* out = (float*)d_out;

    char* ws = (char*)d_ws;
    float*    b1p = (float*)ws;                          // 2048*128 f32 = 1 MiB
    _Float16* w1T = (_Float16*)(ws + 1048576);           // 8192 halfs  = 16 KiB
    _Float16* w2T = (_Float16*)(ws + 1048576 + 16384);   // 16384 halfs = 32 KiB
    _Float16* w3T = (_Float16*)(ws + 1048576 + 16384 + 32768);

    wconv<<<160, 256, 0, stream>>>(w1, w2, w3, w1T, w2T, w3T);
    enc_pool<<<BSEG, 256, 0, stream>>>(points, batch, w_ne, b_ne, w1, b1, b1p);
    fused_mlp<<<BSEG, 256, 0, stream>>>(feat, batch, b1p, w1T, w2T, w3T,
                                        b2, b3, wg1, bg1, wg2, bg2, wg3, bg3, out);
}

// Round 4
// 558.099 us; speedup vs baseline: 1.0174x; 1.0174x over previous
//
#include <hip/hip_runtime.h>
#include <hip/hip_fp16.h>

// Problem constants (fixed by reference)
#define N_PTS 1048576
#define BSEG  2048
#define XSTR  104   // x-tile row stride (halfs): 64 feat + 32 enc + 8 pad = 208 B (13*16)
#define NSLOT 8     // per-block segment slots (256-row block spans ~1-2 segs)

typedef _Float16 half8  __attribute__((ext_vector_type(8)));
typedef _Float16 half4  __attribute__((ext_vector_type(4)));
typedef float    floatx4 __attribute__((ext_vector_type(4)));
typedef int      intx4   __attribute__((ext_vector_type(4)));

// ---------------------------------------------------------------------------
// Kernel W: transpose + f16-convert heavy-layer weights.
// x-tile K layout is [feat(64) | enc(32)]; w1 rows 32..95 are the feat part,
// rows 0..31 the enc part -> w1T [128 j][96 k] reordered to match.
// w2/w3 -> [128 j][128 k].
// ---------------------------------------------------------------------------
__global__ __launch_bounds__(256) void wconv(const float* __restrict__ w1,
                                             const float* __restrict__ w2,
                                             const float* __restrict__ w3,
                                             _Float16* __restrict__ w1T,
                                             _Float16* __restrict__ w2T,
                                             _Float16* __restrict__ w3T) {
    int idx = blockIdx.x * 256 + threadIdx.x;
    if (idx < 12288) {                        // 128*96
        int j = idx / 96, k = idx % 96;
        w1T[idx] = (_Float16)((k < 64) ? w1[(32 + k) * 128 + j] : w1[(k - 64) * 128 + j]);
    } else if (idx < 12288 + 16384) {
        int i = idx - 12288; int j = i >> 7, k = i & 127;
        w2T[i] = (_Float16)w2[k * 128 + j];
    } else if (idx < 12288 + 32768) {
        int i = idx - 12288 - 16384; int j = i >> 7, k = i & 127;
        w3T[i] = (_Float16)w3[k * 128 + j];
    }
}

// ---------------------------------------------------------------------------
// Kernel A: per-segment encoder + segment-max -> enc f16 [2048][32].
// relu>=0 so init-0 max == reference's neginf->0 guard (incl. empty segments).
// ---------------------------------------------------------------------------
__global__ __launch_bounds__(256) void enc_pool(const float* __restrict__ pts,
                                                const int* __restrict__ batch,
                                                const float* __restrict__ wne,
                                                const float* __restrict__ bne,
                                                _Float16* __restrict__ encf) {
    const int b = blockIdx.x, tid = threadIdx.x;
    __shared__ float swne[96];
    __shared__ float sbne[32];
    __shared__ float red[4][32];
    if (tid < 96) swne[tid] = wne[tid];
    if (tid < 32) sbne[tid] = bne[tid];

    int lo = 0, hi = N_PTS;
    while (lo < hi) { int mid = (lo + hi) >> 1; if (batch[mid] < b) lo = mid + 1; else hi = mid; }
    const int start = lo;
    hi = N_PTS;
    while (lo < hi) { int mid = (lo + hi) >> 1; if (batch[mid] < b + 1) lo = mid + 1; else hi = mid; }
    const int end = lo;
    __syncthreads();

    float mx[32];
#pragma unroll
    for (int j = 0; j < 32; j++) mx[j] = 0.f;
    for (int p = start + tid; p < end; p += 256) {
        float x0 = pts[3 * p], x1 = pts[3 * p + 1], x2 = pts[3 * p + 2];
#pragma unroll
        for (int j = 0; j < 32; j++) {
            float e = fmaf(x0, swne[j], fmaf(x1, swne[32 + j], fmaf(x2, swne[64 + j], sbne[j])));
            mx[j] = fmaxf(mx[j], e);
        }
    }
#pragma unroll
    for (int j = 0; j < 32; j++) {
#pragma unroll
        for (int off = 1; off < 64; off <<= 1)
            mx[j] = fmaxf(mx[j], __shfl_xor(mx[j], off, 64));
    }
    const int wv = tid >> 6;
    if ((tid & 63) == 0) {
#pragma unroll
        for (int j = 0; j < 32; j++) red[wv][j] = mx[j];
    }
    __syncthreads();
    if (tid < 32) {
        float v = fmaxf(fmaxf(red[0][tid], red[1][tid]), fmaxf(red[2][tid], red[3][tid]));
        encf[b * 32 + tid] = (_Float16)v;
    }
}

// ---------------------------------------------------------------------------
// Kernel B: segment-AGNOSTIC fused 3-layer MLP. Grid = 4096 blocks x 256
// consecutive rows (exactly 1M: no tails, no binary search, uniform 4 phases
// of 64 rows). 256 threads = 4 waves, jsplit=4 (wave owns 32 cols, B-frags
// VGPR-resident = 88 regs). enc gathered per-row into x-tile (K=96).
// Segment-max: LDS slot table (seg-seg0) + shuffle fast path, flushed with
// one global atomicMax per (slot,col). LDS ~50.7 KB -> 3 blocks/CU.
// ---------------------------------------------------------------------------
__global__ __launch_bounds__(256, 3) void fused_mlp(
    const float* __restrict__ feat, const int* __restrict__ batch,
    const _Float16* __restrict__ encf,
    const _Float16* __restrict__ w1T, const _Float16* __restrict__ w2T,
    const _Float16* __restrict__ w3T,
    const float* __restrict__ b1, const float* __restrict__ b2,
    const float* __restrict__ b3,
    int* __restrict__ pg) {
    __shared__ __attribute__((aligned(16))) _Float16 xf[64 * XSTR];   // 13.3 KB
    __shared__ __attribute__((aligned(16))) _Float16 h1s[64 * 128];   // 16 KB
    __shared__ __attribute__((aligned(16))) _Float16 h2s[64 * 128];   // 16 KB
    __shared__ __attribute__((aligned(16))) int sbat[2][64];
    __shared__ int pooled_s[NSLOT * 128];                             // 4 KB

    const int tid = threadIdx.x;
    const int lane = tid & 63, jq = tid >> 6;
    const int l15 = lane & 15, quad = lane >> 4;
    const int rowbase = blockIdx.x << 8;
    const int seg0 = batch[rowbase];
    const int segN = batch[rowbase + 255];

#pragma unroll
    for (int i = 0; i < 4; i++) pooled_s[i * 256 + tid] = 0;

    // B-fragments (weights), VGPR-resident: 22 half8 = 88 regs.
    // frag layout: elem t of lane = W[n = jcol][k = ks*32 + quad*8 + t]
    const int jc0 = jq * 32 + l15, jc1 = jc0 + 16;
    half8 w1f[2][3], w2f[2][4], w3f[2][4];
#pragma unroll
    for (int ks = 0; ks < 3; ks++) {
        w1f[0][ks] = *(const half8*)(w1T + jc0 * 96 + ks * 32 + quad * 8);
        w1f[1][ks] = *(const half8*)(w1T + jc1 * 96 + ks * 32 + quad * 8);
    }
#pragma unroll
    for (int ks = 0; ks < 4; ks++) {
        w2f[0][ks] = *(const half8*)(w2T + jc0 * 128 + ks * 32 + quad * 8);
        w2f[1][ks] = *(const half8*)(w2T + jc1 * 128 + ks * 32 + quad * 8);
        w3f[0][ks] = *(const half8*)(w3T + jc0 * 128 + ks * 32 + quad * 8);
        w3f[1][ks] = *(const half8*)(w3T + jc1 * 128 + ks * 32 + quad * 8);
    }
    float bb1[2], bb2[2], bb3[2];
    bb1[0] = b1[jc0]; bb1[1] = b1[jc1];
    bb2[0] = b2[jc0]; bb2[1] = b2[jc1];
    bb3[0] = b3[jc0]; bb3[1] = b3[jc1];

    // staging: thread -> (row = tid>>2, 4 x float4 chunks) + enc half8 + batch
    const int srow = tid >> 2, sc4 = tid & 3;
    floatx4 pf[4]; half8 pe; int pb;
    auto issue = [&](int p) {
        const int r = rowbase + p * 64 + srow;
        pb = batch[r];
        const float* fr = feat + (size_t)r * 64;
#pragma unroll
        for (int i = 0; i < 4; i++) pf[i] = *(const floatx4*)(fr + sc4 * 4 + i * 16);
        pe = *(const half8*)(encf + pb * 32 + sc4 * 8);
    };
    auto commit = [&](int p) {
        _Float16* xr = &xf[srow * XSTR];
#pragma unroll
        for (int i = 0; i < 4; i++) {
            half4 hv = {(_Float16)pf[i].x, (_Float16)pf[i].y, (_Float16)pf[i].z, (_Float16)pf[i].w};
            *(half4*)(xr + sc4 * 4 + i * 16) = hv;
        }
        *(half8*)(xr + 64 + sc4 * 8) = pe;
        if (sc4 == 0) sbat[p & 1][srow] = pb;
    };
    // swizzled h store/read: elem (row, col c) at row*128 + (((c>>3)^(row&15))&15)*8 + (c&7)
    auto storeH = [&](_Float16* hbuf, int mt, floatx4* acc, float* bb) {
#pragma unroll
        for (int jt = 0; jt < 2; jt++) {
            int c = jq * 32 + jt * 16 + l15;
#pragma unroll
            for (int r = 0; r < 4; r++) {
                int rr = quad * 4 + r;
                float v = fmaxf(acc[jt][r] + bb[jt], 0.f);
                hbuf[(mt * 16 + rr) * 128 + ((((c >> 3) ^ rr) & 15) << 3) + (c & 7)] = (_Float16)v;
            }
        }
    };

    // prologue
    issue(0); commit(0); issue(1);
    __syncthreads();

    for (int p = 0; p < 4; ++p) {
        floatx4 acc[2];
        // ---- Layer 1: xf (K=96) -> h1 ----
#pragma unroll
        for (int mt = 0; mt < 4; mt++) {
            half8 a[3];
#pragma unroll
            for (int ks = 0; ks < 3; ks++)
                a[ks] = *(const half8*)(&xf[(mt * 16 + l15) * XSTR + ks * 32 + quad * 8]);
            acc[0] = (floatx4){0.f, 0.f, 0.f, 0.f};
            acc[1] = (floatx4){0.f, 0.f, 0.f, 0.f};
#pragma unroll
            for (int ks = 0; ks < 3; ks++) {
                acc[0] = __builtin_amdgcn_mfma_f32_16x16x32_f16(a[ks], w1f[0][ks], acc[0], 0, 0, 0);
                acc[1] = __builtin_amdgcn_mfma_f32_16x16x32_f16(a[ks], w1f[1][ks], acc[1], 0, 0, 0);
            }
            storeH(h1s, mt, acc, bb1);
        }
        __syncthreads();   // B1: h1 ready; xf readers done

        // ---- staging for later phases (xf single-buffered: fenced by B1/B2) ----
        if (p + 1 < 4) commit(p + 1);
        if (p + 2 < 4) issue(p + 2);

        // ---- Layer 2: h1 (K=128) -> h2 ----
#pragma unroll
        for (int mt = 0; mt < 4; mt++) {
            half8 a[4];
#pragma unroll
            for (int ks = 0; ks < 4; ks++)
                a[ks] = *(const half8*)(&h1s[((mt * 16 + l15) << 7) + ((((ks * 4 + quad) ^ l15) & 15) << 3)]);
            acc[0] = (floatx4){0.f, 0.f, 0.f, 0.f};
            acc[1] = (floatx4){0.f, 0.f, 0.f, 0.f};
#pragma unroll
            for (int ks = 0; ks < 4; ks++) {
                acc[0] = __builtin_amdgcn_mfma_f32_16x16x32_f16(a[ks], w2f[0][ks], acc[0], 0, 0, 0);
                acc[1] = __builtin_amdgcn_mfma_f32_16x16x32_f16(a[ks], w2f[1][ks], acc[1], 0, 0, 0);
            }
            storeH(h2s, mt, acc, bb2);
        }
        __syncthreads();   // B2: h2 + new xf ready

        // ---- Layer 3: h2 (K=128) -> segment-max pooling ----
#pragma unroll
        for (int mt = 0; mt < 4; mt++) {
            half8 a[4];
#pragma unroll
            for (int ks = 0; ks < 4; ks++)
                a[ks] = *(const half8*)(&h2s[((mt * 16 + l15) << 7) + ((((ks * 4 + quad) ^ l15) & 15) << 3)]);
            acc[0] = (floatx4){0.f, 0.f, 0.f, 0.f};
            acc[1] = (floatx4){0.f, 0.f, 0.f, 0.f};
#pragma unroll
            for (int ks = 0; ks < 4; ks++) {
                acc[0] = __builtin_amdgcn_mfma_f32_16x16x32_f16(a[ks], w3f[0][ks], acc[0], 0, 0, 0);
                acc[1] = __builtin_amdgcn_mfma_f32_16x16x32_f16(a[ks], w3f[1][ks], acc[1], 0, 0, 0);
            }
            const int sA = sbat[p & 1][mt * 16];
            const int sB = sbat[p & 1][mt * 16 + 15];
            if (sA == sB) {
                // fast path: whole 16-row tile in one segment
                const int slot = sA - seg0;
#pragma unroll
                for (int jt = 0; jt < 2; jt++) {
                    float m = fmaxf(fmaxf(fmaxf(acc[jt][0], acc[jt][1]),
                                          fmaxf(acc[jt][2], acc[jt][3])) + bb3[jt], 0.f);
                    m = fmaxf(m, __shfl_xor(m, 16, 64));
                    m = fmaxf(m, __shfl_xor(m, 32, 64));
                    if (quad == 0) {
                        int vi = __float_as_int(m);
                        if (vi) {
                            int col = jq * 32 + jt * 16 + l15;
                            if (slot < NSLOT) atomicMax(&pooled_s[slot * 128 + col], vi);
                            else              atomicMax(&pg[sA * 128 + col], vi);
                        }
                    }
                }
            } else {
                // boundary tile: per-row slots
                intx4 sb4 = *(const intx4*)&sbat[p & 1][mt * 16 + quad * 4];
#pragma unroll
                for (int jt = 0; jt < 2; jt++) {
                    int col = jq * 32 + jt * 16 + l15;
#pragma unroll
                    for (int r = 0; r < 4; r++) {
                        float v = fmaxf(acc[jt][r] + bb3[jt], 0.f);
                        int vi = __float_as_int(v);
                        if (vi) {
                            int sg = sb4[r], slot = sg - seg0;
                            if (slot < NSLOT) atomicMax(&pooled_s[slot * 128 + col], vi);
                            else              atomicMax(&pg[sg * 128 + col], vi);
                        }
                    }
                }
            }
        }
        // no barrier: next L1 reads xf (fenced by B2) and writes h1 (readers
        // done at B2); h2 next written after next B1 > this L3.
    }

    __syncthreads();
    // flush LDS slots -> global atomicMax (skip zeros: init is 0)
    const int span = segN - seg0 + 1;
#pragma unroll
    for (int i = 0; i < 4; i++) {
        int idx = i * 256 + tid;
        int slot = idx >> 7, col = idx & 127;
        if (slot < span) {
            int v = pooled_s[idx];
            if (v) atomicMax(&pg[(seg0 + slot) * 128 + col], v);
        }
    }
}

// ---------------------------------------------------------------------------
// Kernel C: tiny fp32 head MLP per segment.
// ---------------------------------------------------------------------------
__global__ __launch_bounds__(128) void head(const float* __restrict__ pooled,
                                            const float* __restrict__ wg1, const float* __restrict__ bg1,
                                            const float* __restrict__ wg2, const float* __restrict__ bg2,
                                            const float* __restrict__ wg3, const float* __restrict__ bg3,
                                            float* __restrict__ out) {
    const int b = blockIdx.x, tid = threadIdx.x;
    __shared__ float sp[128], g1[128], g2[64];
    sp[tid] = pooled[b * 128 + tid];
    __syncthreads();
    float a = bg1[tid];
#pragma unroll 8
    for (int k = 0; k < 128; k++) a = fmaf(sp[k], wg1[k * 128 + tid], a);
    g1[tid] = fmaxf(a, 0.f);
    __syncthreads();
    if (tid < 64) {
        float c = bg2[tid];
#pragma unroll 8
        for (int k = 0; k < 128; k++) c = fmaf(g1[k], wg2[k * 64 + tid], c);
        g2[tid] = fmaxf(c, 0.f);
    }
    __syncthreads();
    if (tid < 32) {
        float c = bg3[tid];
#pragma unroll 8
        for (int k = 0; k < 64; k++) c = fmaf(g2[k], wg3[k * 32 + tid], c);
        out[b * 32 + tid] = fmaxf(c, 0.f);
    }
}

// ---------------------------------------------------------------------------
extern "C" void kernel_launch(void* const* d_in, const int* in_sizes, int n_in,
                              void* d_out, int out_size, void* d_ws, size_t ws_size,
                              hipStream_t stream) {
    const float* points = (const float*)d_in[0];
    const float* feat   = (const float*)d_in[1];
    const int*   batch  = (const int*)d_in[2];
    const float* w_ne   = (const float*)d_in[3];
    const float* b_ne   = (const float*)d_in[4];
    const float* w1  = (const float*)d_in[5];
    const float* b1  = (const float*)d_in[6];
    const float* w2  = (const float*)d_in[7];
    const float* b2  = (const float*)d_in[8];
    const float* w3  = (const float*)d_in[9];
    const float* b3  = (const float*)d_in[10];
    const float* wg1 = (const float*)d_in[11];
    const float* bg1 = (const float*)d_in[12];
    const float* wg2 = (const float*)d_in[13];
    const float* bg2 = (const float*)d_in[14];
    const float* wg3 = (const float*)d_in[15];
    const float* bg3 = (const float*)d_in[16];
    float* out = (float*)d_out;

    char* ws = (char*)d_ws;
    int*      pg   = (int*)ws;                            // 2048*128 i32 = 1 MiB
    _Float16* encf = (_Float16*)(ws + 1048576);           // 2048*32 f16 = 128 KiB
    _Float16* w1T  = (_Float16*)(ws + 1048576 + 131072);  // 12288 halfs = 24 KiB
    _Float16* w2T  = (_Float16*)(ws + 1048576 + 131072 + 24576);
    _Float16* w3T  = (_Float16*)(ws + 1048576 + 131072 + 24576 + 32768);

    hipMemsetAsync(pg, 0, BSEG * 128 * sizeof(int), stream);
    wconv<<<176, 256, 0, stream>>>(w1, w2, w3, w1T, w2T, w3T);
    enc_pool<<<BSEG, 256, 0, stream>>>(points, batch, w_ne, b_ne, encf);
    fused_mlp<<<4096, 256, 0, stream>>>(feat, batch, encf, w1T, w2T, w3T,
                                        b1, b2, b3, pg);
    head<<<BSEG, 128, 0, stream>>>((const float*)pg, wg1, bg1, wg2, bg2, wg3, bg3, out);
}